// Round 2
// baseline (266.180 us; speedup 1.0000x reference)
//
#include <hip/hip_runtime.h>

#define DHW    65536
#define NCH    256
#define NNODE  7
#define NHID   128
#define NBATCH 2

// ---------------------------------------------------------------------------
// Prep kernel:
//   nwt[b][c][8]  = new_weight transposed+padded: sum_h inp[b,n,h]*weight[h,c]
//   n2g[b][8]     = inp[b,n,:] . node_fea_for_hidden
//   w1p[c][8]     = node_fea_for_res padded 7->8 (block 0 only)
// Grid: 14 blocks (b*7+n), 256 threads (one per c).
// ---------------------------------------------------------------------------
__global__ void prep_kernel(const float* __restrict__ inp,
                            const float* __restrict__ nfh,
                            const float* __restrict__ weight,
                            const float* __restrict__ w1,
                            float* __restrict__ nwt,   // [2][256][8]
                            float* __restrict__ n2g,   // [2][8]
                            float* __restrict__ w1p)   // [256][8]
{
    const int bn = blockIdx.x;
    const int b  = bn / NNODE;
    const int n  = bn % NNODE;
    const int t  = threadIdx.x;            // c index
    const float* ih = inp + (b * NNODE + n) * NHID;

    float acc = 0.f;
    #pragma unroll 8
    for (int h = 0; h < NHID; ++h)
        acc = fmaf(ih[h], weight[h * NCH + t], acc);
    nwt[(b * NCH + t) * 8 + n] = acc;

    if (bn == 0) {
        #pragma unroll
        for (int n2 = 0; n2 < NNODE; ++n2) w1p[t * 8 + n2] = w1[t * NNODE + n2];
        w1p[t * 8 + 7] = 0.f;
    }

    __shared__ float red[NHID];
    if (t < NHID) red[t] = ih[t] * nfh[t];
    __syncthreads();
    for (int s = NHID / 2; s > 0; s >>= 1) {
        if (t < s) red[t] += red[t + s];
        __syncthreads();
    }
    if (t == 0) n2g[b * 8 + n] = red[0];
}

// ---------------------------------------------------------------------------
// Main kernel: block = 64 points, 4 waves; wave w owns channels [64w, 64w+64).
// Phase 1: per-wave partial scores (64 ch), LDS cross-wave reduce, softmax.
// Phase 2: each wave writes its 64 output channels.
// Grid: 2048 blocks x 256 threads -> 8 blocks/CU -> 32 waves/CU.
// Weight tables read via wave-uniform indices -> scalar loads (no in-loop LDS).
// ---------------------------------------------------------------------------
__global__ __launch_bounds__(256, 8)
void main_kernel(const float* __restrict__ rf,    // [2][256][65536]
                 const float* __restrict__ w1p,   // [256][8]
                 const float* __restrict__ nwt,   // [2][256][8]
                 const float* __restrict__ n2g,   // [2][8]
                 float* __restrict__ out)         // [2][256][65536]
{
    __shared__ float red[8][4][64];   // [node][wave][point-lane], 8 KiB

    const int t    = threadIdx.x;
    const int lane = t & 63;
    const int wv   = __builtin_amdgcn_readfirstlane(t >> 6);  // 0..3, uniform
    const int blk  = blockIdx.x;                              // 0..2047
    const int b    = blk >> 10;
    const int p    = ((blk & 1023) << 6) + lane;
    const int c0   = wv << 6;

    // ---- Phase 1: partial scores over this wave's 64 channels -----------
    const float*  rp = rf + ((size_t)b << 24) + ((size_t)c0 << 16) + p;
    const float4* wq = (const float4*)w1p + (c0 << 1);  // 2 float4 per channel

    float s0 = 0.f, s1 = 0.f, s2 = 0.f, s3 = 0.f, s4 = 0.f, s5 = 0.f, s6 = 0.f;
    #pragma unroll 8
    for (int c = 0; c < 64; ++c) {
        float  v  = rp[(size_t)c << 16];
        float4 wa = wq[c * 2];        // uniform -> s_load
        float4 wb = wq[c * 2 + 1];
        s0 = fmaf(v, wa.x, s0);
        s1 = fmaf(v, wa.y, s1);
        s2 = fmaf(v, wa.z, s2);
        s3 = fmaf(v, wa.w, s3);
        s4 = fmaf(v, wb.x, s4);
        s5 = fmaf(v, wb.y, s5);
        s6 = fmaf(v, wb.z, s6);
    }

    // ---- Cross-wave reduction (conflict-free: lane-consecutive) ---------
    red[0][wv][lane] = s0;  red[1][wv][lane] = s1;  red[2][wv][lane] = s2;
    red[3][wv][lane] = s3;  red[4][wv][lane] = s4;  red[5][wv][lane] = s5;
    red[6][wv][lane] = s6;
    __syncthreads();

    const float* n2 = n2g + b * 8;   // uniform -> scalar loads
    float r0 = red[0][0][lane] + red[0][1][lane] + red[0][2][lane] + red[0][3][lane] + n2[0];
    float r1 = red[1][0][lane] + red[1][1][lane] + red[1][2][lane] + red[1][3][lane] + n2[1];
    float r2 = red[2][0][lane] + red[2][1][lane] + red[2][2][lane] + red[2][3][lane] + n2[2];
    float r3 = red[3][0][lane] + red[3][1][lane] + red[3][2][lane] + red[3][3][lane] + n2[3];
    float r4 = red[4][0][lane] + red[4][1][lane] + red[4][2][lane] + red[4][3][lane] + n2[4];
    float r5 = red[5][0][lane] + red[5][1][lane] + red[5][2][lane] + red[5][3][lane] + n2[5];
    float r6 = red[6][0][lane] + red[6][1][lane] + red[6][2][lane] + red[6][3][lane] + n2[6];

    // ---- Softmax over 7 nodes (redundant per wave, cheap) ---------------
    float m = fmaxf(fmaxf(fmaxf(r0, r1), fmaxf(r2, r3)),
                    fmaxf(fmaxf(r4, r5), r6));
    float e0 = __expf(r0 - m), e1 = __expf(r1 - m), e2 = __expf(r2 - m);
    float e3 = __expf(r3 - m), e4 = __expf(r4 - m), e5 = __expf(r5 - m);
    float e6 = __expf(r6 - m);
    float inv = 1.0f / (e0 + e1 + e2 + e3 + e4 + e5 + e6);
    float a0 = e0 * inv, a1 = e1 * inv, a2 = e2 * inv, a3 = e3 * inv;
    float a4 = e4 * inv, a5 = e5 * inv, a6 = e6 * inv;

    // ---- Phase 2: this wave's 64 output channels ------------------------
    const float4* nq = (const float4*)nwt + ((b * NCH + c0) << 1);  // uniform
    float* op = out + ((size_t)b << 24) + ((size_t)c0 << 16) + p;
    #pragma unroll 8
    for (int c = 0; c < 64; ++c) {
        float4 na = nq[c * 2];        // uniform -> s_load
        float4 nb = nq[c * 2 + 1];
        float o = a0 * na.x + a1 * na.y + a2 * na.z + a3 * na.w
                + a4 * nb.x + a5 * nb.y + a6 * nb.z;
        op[(size_t)c << 16] = fmaxf(o, 0.f);
    }
}

extern "C" void kernel_launch(void* const* d_in, const int* in_sizes, int n_in,
                              void* d_out, int out_size, void* d_ws, size_t ws_size,
                              hipStream_t stream) {
    const float* inp = (const float*)d_in[0];   // (1,2,7,128)
    const float* rf  = (const float*)d_in[1];   // (2,256,16,64,64)
    const float* w1  = (const float*)d_in[2];   // (256,7)
    const float* nfh = (const float*)d_in[3];   // (128,1)
    const float* wgt = (const float*)d_in[4];   // (128,256)
    float* out = (float*)d_out;

    float* nwt = (float*)d_ws;                  // [2][256][8]
    float* n2g = nwt + NBATCH * NCH * 8;        // [2][8]
    float* w1p = n2g + NBATCH * 8;              // [256][8]

    prep_kernel<<<NBATCH * NNODE, 256, 0, stream>>>(inp, nfh, wgt, w1, nwt, n2g, w1p);
    main_kernel<<<NBATCH * 1024, 256, 0, stream>>>(rf, w1p, nwt, n2g, out);
}